// Round 13
// baseline (209.575 us; speedup 1.0000x reference)
//
#include <hip/hip_runtime.h>

#define N_NODES 50000
#define N_EDGES 1600000
#define DIM 64
#define NBK 196          // buckets of 256 dst-nodes
#define BIN_BLOCKS 391   // ceil(1.6M / 4096)
#define CSR_CAP 12288    // per-bucket binned slots = 8 octants x OCT_CAP
#define OCT_CAP 1536     // per-(bucket,octant) slots (mean ~1021, +16 sigma)
#define BCAP 13312       // per-bucket csr16 slots (mean 8192 + pad<=3840 + 14-sigma)
#define G1_BLOCKS 391    // gemm1 half: 391*128 = 50048 >= 50001 nodes (incl. dummy)
#define NB_AGG8 6250     // agg blocks (8 nodes/block; 6250*8 == 50000 exactly)

// f32 -> bf16 round-to-nearest-even
__device__ __forceinline__ unsigned short f2bf(float f) {
    union { float f; unsigned u; } v; v.f = f;
    unsigned r = v.u + 0x7FFF + ((v.u >> 16) & 1);
    return (unsigned short)(r >> 16);
}
__device__ __forceinline__ float bf2f(unsigned short h) {
    union { unsigned u; float f; } v; v.u = ((unsigned)h) << 16;  return v.f;
}
// packed-bf16 halves of a uint -> f32 (low ushort, high ushort)
__device__ __forceinline__ float blo(unsigned u) {
    union { unsigned u; float f; } v; v.u = u << 16; return v.f;
}
__device__ __forceinline__ float bhi(unsigned u) {
    union { unsigned u; float f; } v; v.u = u & 0xFFFF0000u; return v.f;
}

// R26: fused binning + GEMM1. Binning scan is now a SINGLE-WAVE shuffle
// prefix: wave 0 reads all 256 counters (4/lane), 6-round __shfl_up scan,
// writes lofs + issues bcur atomics. Block barriers drop 21 -> 4.
// R25 post-mortem ledger: bin cost invariant to atomic contention (R20),
// block size (R22), load chain (R24), LDS op count (R25) -- the 16-barrier
// Hillis-Steele scan is the only untested structure big enough (~1-2K cy
// rendezvous x 21 barriers at 12-16 resident waves), and explains the 8%
// occupancy (barrier-parked waves don't issue).
__global__ __launch_bounds__(256) void bin_gemm1(const int* __restrict__ src,
                                                 const int* __restrict__ dst,
                                                 int* __restrict__ bcur,
                                                 int* __restrict__ binned,
                                                 const float* __restrict__ X,
                                                 const float* __restrict__ W,
                                                 unsigned short* __restrict__ T) {
    __shared__ __align__(16) char smem[35840];   // bin: 3KB ctrl + 32KB stag2; gemm: 32KB xs
    int tid = threadIdx.x;

    if (blockIdx.x >= BIN_BLOCKS) {
        // ---------------- GEMM path (R21-proven): T = X @ W^T ----------------
        float4* xs = (float4*)smem;      // 128 node rows x 16 float4 = 32KB
        int w = tid >> 6, lane = tid & 63;
        int nbase = (blockIdx.x - BIN_BLOCKS) * 128;

        float4 wreg[16];
        const float4* wp = (const float4*)(W + lane * 64);
#pragma unroll
        for (int k4 = 0; k4 < 16; ++k4) wreg[k4] = wp[k4];

        const float4* xg = (const float4*)X;
        for (int L = tid; L < 2048; L += 256) {
            int row = nbase + (L >> 4);
            float4 v = {0.f, 0.f, 0.f, 0.f};
            if (row < N_NODES) v = xg[(size_t)row * 16 + (L & 15)];
            xs[L] = v;
        }
        __syncthreads();

        for (int g = 0; g < 8; ++g) {
            int n0 = w * 32 + g * 4;
            float accA = 0.f, accB = 0.f, accC = 0.f, accD = 0.f;
#pragma unroll
            for (int k4 = 0; k4 < 16; ++k4) {
                float4 w4 = wreg[k4];
                float4 xA = xs[(n0 + 0) * 16 + k4];   // wave-uniform -> broadcast
                float4 xB = xs[(n0 + 1) * 16 + k4];
                float4 xC = xs[(n0 + 2) * 16 + k4];
                float4 xD = xs[(n0 + 3) * 16 + k4];
                accA += xA.x * w4.x + xA.y * w4.y + xA.z * w4.z + xA.w * w4.w;
                accB += xB.x * w4.x + xB.y * w4.y + xB.z * w4.z + xB.w * w4.w;
                accC += xC.x * w4.x + xC.y * w4.y + xC.z * w4.z + xC.w * w4.w;
                accD += xD.x * w4.x + xD.y * w4.y + xD.z * w4.z + xD.w * w4.w;
            }
            int gn = nbase + n0;
            unsigned short vA = (gn + 0 == N_NODES) ? (unsigned short)0 : f2bf(accA);
            unsigned short vB = (gn + 1 == N_NODES) ? (unsigned short)0 : f2bf(accB);
            unsigned short vC = (gn + 2 == N_NODES) ? (unsigned short)0 : f2bf(accC);
            unsigned short vD = (gn + 3 == N_NODES) ? (unsigned short)0 : f2bf(accD);
            if (gn + 0 <= N_NODES) T[(size_t)(gn + 0) * 64 + lane] = vA;
            if (gn + 1 <= N_NODES) T[(size_t)(gn + 1) * 64 + lane] = vB;
            if (gn + 2 <= N_NODES) T[(size_t)(gn + 2) * 64 + lane] = vC;
            if (gn + 3 <= N_NODES) T[(size_t)(gn + 3) * 64 + lane] = vD;
        }
        return;
    }

    // ---- Binning path (R24 phase-split + R25 8B records + R26 wave scan) ----
    int* cnt    = (int*)smem;            // 256 ints (196..255 stay zero)
    int* lofs   = cnt + 256;
    int* shiftv = lofs + 256;
    uint2* stag2 = (uint2*)(shiftv + 256);   // 4096 x 8B = 32KB

    cnt[tid] = 0;
    __syncthreads();

    int base = blockIdx.x * 4096;
    int oct = blockIdx.x & 7;
    int nedge = N_EDGES - base;
    if (nedge > 4096) nedge = 4096;

    // Phase 1: pure load loop -- 32 independent global loads in flight (R24)
    int sreg[16], dreg[16];
#pragma unroll
    for (int i = 0; i < 16; ++i) {
        int e = base + i * 256 + tid;
        if (e < N_EDGES) { sreg[i] = src[e]; dreg[i] = dst[e]; }
        else             { sreg[i] = 0;      dreg[i] = -1; }
    }
    // Phase 2: LDS histogram with rank
    int myr[16];
#pragma unroll
    for (int i = 0; i < 16; ++i)
        if (dreg[i] >= 0) myr[i] = atomicAdd(&cnt[dreg[i] >> 8], 1);
    __syncthreads();

    // Phase 3 (R26): single-wave shuffle scan, zero barriers inside.
    if (tid < 64) {
        int c0 = cnt[tid * 4 + 0];
        int c1 = cnt[tid * 4 + 1];
        int c2 = cnt[tid * 4 + 2];
        int c3 = cnt[tid * 4 + 3];
        int t = c0 + c1 + c2 + c3;
        int p = t;
#pragma unroll
        for (int off = 1; off < 64; off <<= 1) {
            int u = __shfl_up(p, off);
            if (tid >= off) p += u;
        }
        int ex = p - t;                  // exclusive prefix of this lane's 4 buckets
        int b0 = tid * 4;
        lofs[b0 + 0] = ex;
        lofs[b0 + 1] = ex + c0;
        lofs[b0 + 2] = ex + c0 + c1;
        lofs[b0 + 3] = ex + c0 + c1 + c2;
        // per-bucket global region reservation (independent atomics)
        if (b0 + 0 < NBK && c0) shiftv[b0 + 0] = (b0 + 0) * CSR_CAP + oct * OCT_CAP
            + atomicAdd(&bcur[((b0 + 0) * 8 + oct) * 16], c0) - lofs[b0 + 0];
        if (b0 + 1 < NBK && c1) shiftv[b0 + 1] = (b0 + 1) * CSR_CAP + oct * OCT_CAP
            + atomicAdd(&bcur[((b0 + 1) * 8 + oct) * 16], c1) - lofs[b0 + 1];
        if (b0 + 2 < NBK && c2) shiftv[b0 + 2] = (b0 + 2) * CSR_CAP + oct * OCT_CAP
            + atomicAdd(&bcur[((b0 + 2) * 8 + oct) * 16], c2) - lofs[b0 + 2];
        if (b0 + 3 < NBK && c3) shiftv[b0 + 3] = (b0 + 3) * CSR_CAP + oct * OCT_CAP
            + atomicAdd(&bcur[((b0 + 3) * 8 + oct) * 16], c3) - lofs[b0 + 3];
    }
    __syncthreads();

    // Phase 4: single b64 staging write per edge (payload + bucket)
#pragma unroll
    for (int i = 0; i < 16; ++i) {
        if (dreg[i] >= 0) {
            int b = dreg[i] >> 8;
            uint2 rec;
            rec.x = (unsigned)(((dreg[i] & 255) << 16) | sreg[i]);
            rec.y = (unsigned)b;
            stag2[lofs[b] + myr[i]] = rec;
        }
    }
    __syncthreads();

    // Phase 5: single b64 read per edge, semi-coalesced global write
    for (int i = tid; i < nedge; i += 256) {
        uint2 v = stag2[i];
        binned[i + shiftv[v.y]] = (int)v.x;
    }
}

// R24-verbatim build_csr (single-pass per bucket + depth-4 prefetch).
__global__ __launch_bounds__(256) void build_csr(const int* __restrict__ binned,
                                                 const int* __restrict__ bcur,
                                                 unsigned* __restrict__ nodeinfo,
                                                 unsigned short* __restrict__ csr16) {
    __shared__ int cnt[256], cnt2[256], ofs[256], sb[256];
    __shared__ int mo[8];
    int tid = threadIdx.x;
    int b = blockIdx.x;
    int bbase = b * BCAP;
    cnt[tid] = 0; cnt2[tid] = 0;
    if (tid < 8) {
        int m = bcur[(b * 8 + tid) * 16];
        mo[tid] = m > OCT_CAP ? OCT_CAP : m;
    }
    __syncthreads();

    for (int oct = 0; oct < 8; ++oct) {
        const int* ib = binned + b * CSR_CAP + oct * OCT_CAP;
        int m = mo[oct];
        int i = tid;
        for (; i + 768 < m; i += 1024) {
            int p0 = ib[i], p1 = ib[i + 256], p2 = ib[i + 512], p3 = ib[i + 768];
            atomicAdd(&cnt[(p0 >> 16) & 255], 1);
            atomicAdd(&cnt[(p1 >> 16) & 255], 1);
            atomicAdd(&cnt[(p2 >> 16) & 255], 1);
            atomicAdd(&cnt[(p3 >> 16) & 255], 1);
        }
        for (; i < m; i += 256)
            atomicAdd(&cnt[(ib[i] >> 16) & 255], 1);
    }
    __syncthreads();

    int myc = cnt[tid];
    int v = (myc + 15) & ~15;          // mult-16 pad
    sb[tid] = v;
    __syncthreads();
    for (int off = 1; off < 256; off <<= 1) {
        int u = (tid >= off) ? sb[tid - off] : 0;
        __syncthreads();
        sb[tid] += u;
        __syncthreads();
    }
    int o = sb[tid] - v;
    ofs[tid] = o;
    int node = (b << 8) + tid;
    if (node < N_NODES)
        nodeinfo[node] = ((unsigned)v << 23) | (unsigned)(bbase + o);
    for (int i = myc; i < v; ++i)       // pad tail with dummy src
        csr16[bbase + o + i] = (unsigned short)N_NODES;
    __syncthreads();

    for (int oct = 0; oct < 8; ++oct) {
        const int* ib = binned + b * CSR_CAP + oct * OCT_CAP;
        int m = mo[oct];
        int i = tid;
        for (; i + 768 < m; i += 1024) {
            int p0 = ib[i], p1 = ib[i + 256], p2 = ib[i + 512], p3 = ib[i + 768];
            int d0 = (p0 >> 16) & 255, d1 = (p1 >> 16) & 255;
            int d2 = (p2 >> 16) & 255, d3 = (p3 >> 16) & 255;
            int r0 = atomicAdd(&cnt2[d0], 1);
            int r1 = atomicAdd(&cnt2[d1], 1);
            int r2 = atomicAdd(&cnt2[d2], 1);
            int r3 = atomicAdd(&cnt2[d3], 1);
            csr16[bbase + ofs[d0] + r0] = (unsigned short)(p0 & 0xFFFF);
            csr16[bbase + ofs[d1] + r1] = (unsigned short)(p1 & 0xFFFF);
            csr16[bbase + ofs[d2] + r2] = (unsigned short)(p2 & 0xFFFF);
            csr16[bbase + ofs[d3] + r3] = (unsigned short)(p3 & 0xFFFF);
        }
        for (; i < m; i += 256) {
            int p = ib[i];
            int dl = (p >> 16) & 255;
            int r = atomicAdd(&cnt2[dl], 1);
            csr16[bbase + ofs[dl] + r] = (unsigned short)(p & 0xFFFF);
        }
    }
}

// Accumulate one uint4 (8 bf16 feature values) into 8 f32 accumulators.
#define ACC8(d)                                                     \
    a0 += blo(d.x); a1 += bhi(d.x); a2 += blo(d.y); a3 += bhi(d.y); \
    a4 += blo(d.z); a5 += bhi(d.z); a6 += blo(d.w); a7 += bhi(d.w);

// R23-verbatim agg_fuse1 (at the ~18cy/scattered-request structural floor --
// R17/R19/R22 proved hit-tier/occupancy/request-width invariance).
__global__ __launch_bounds__(512) void agg_fuse1(const unsigned short* __restrict__ T,
                                                 const unsigned short* __restrict__ csr,
                                                 const unsigned* __restrict__ nodeinfo,
                                                 const float* __restrict__ b1,
                                                 const float* __restrict__ W2,
                                                 unsigned short* __restrict__ T2) {
    __shared__ __align__(16) float4 W2t4[1024];     // 16 KB (W2 transposed, lane-striped)
    __shared__ __align__(16) float part[8][8][72];  // 18 KB (per-wave partials; row0 doubles as h)
    int tid = threadIdx.x;
    int w = tid >> 6;
    int lane = tid & 63;
    int g8 = lane >> 3;
    int fs = lane & 7;
    int node = blockIdx.x * 8 + w;

    for (int L4 = tid; L4 < 1024; L4 += 512) {
        int k4 = L4 >> 6, f = L4 & 63;
        W2t4[L4] = *(const float4*)(W2 + f * 64 + k4 * 4);
    }

    unsigned info = nodeinfo[node];
    float bias = b1[lane];
    int pos = (int)(info & 0x7FFFFFu);
    int nch = (int)(info >> 23) >> 3;   // 8-edge chunks, even (pcnt mult 16)
    const unsigned short* ip = csr + pos + g8;
    const uint4* Tp = (const uint4*)T;
    float a0 = 0.f, a1 = 0.f, a2 = 0.f, a3 = 0.f, a4 = 0.f, a5 = 0.f, a6 = 0.f, a7 = 0.f;
    int c = 0;
    for (; c + 4 <= nch; c += 4) {
        int j0 = ip[c * 8];
        int j1 = ip[c * 8 + 8];
        int j2 = ip[c * 8 + 16];
        int j3 = ip[c * 8 + 24];
        uint4 d0 = Tp[j0 * 8 + fs];
        uint4 d1 = Tp[j1 * 8 + fs];
        uint4 d2 = Tp[j2 * 8 + fs];
        uint4 d3 = Tp[j3 * 8 + fs];
        ACC8(d0) ACC8(d1) ACC8(d2) ACC8(d3)
    }
    if (c < nch) {   // remaining 2 chunks (nch even)
        int j0 = ip[c * 8];
        int j1 = ip[c * 8 + 8];
        uint4 d0 = Tp[j0 * 8 + fs];
        uint4 d1 = Tp[j1 * 8 + fs];
        ACC8(d0) ACC8(d1)
    }
    float4 pa = {a0, a1, a2, a3};
    float4 pb = {a4, a5, a6, a7};
    *(float4*)&part[w][g8][fs * 8] = pa;
    *(float4*)&part[w][g8][fs * 8 + 4] = pb;
    __syncthreads();   // covers W2t4 staging (part is wave-private)

    float acc = bias;
#pragma unroll
    for (int g = 0; g < 8; ++g) acc += part[w][g][lane];

    float e = __expf(2.f * acc);
    part[w][0][lane] = 1.f - 2.f / (e + 1.f);   // after all part reads (lockstep wave)

    const float* hrow = &part[w][0][0];
    float tf = 0.f;
#pragma unroll
    for (int k4 = 0; k4 < 16; ++k4) {
        float4 hv = *(const float4*)(hrow + k4 * 4);   // broadcast
        float4 wv = W2t4[k4 * 64 + lane];
        tf += hv.x * wv.x + hv.y * wv.y + hv.z * wv.z + hv.w * wv.w;
    }
    T2[(size_t)node * DIM + lane] = f2bf(tf);

    // zero T2's dummy pad row (block 0 only; agg2 gathers it for padding)
    if (blockIdx.x == 0 && tid < 64)
        T2[(size_t)N_NODES * DIM + tid] = 0;
}

// R23-verbatim agg_out (scattered-gather floor). No barrier.
__global__ __launch_bounds__(512) void agg_out(const unsigned short* __restrict__ T,
                                               const unsigned short* __restrict__ csr,
                                               const unsigned* __restrict__ nodeinfo,
                                               const float* __restrict__ bias,
                                               float* __restrict__ outp) {
    __shared__ __align__(16) float part[8][8][72];  // 18 KB, wave-private
    int tid = threadIdx.x;
    int w = tid >> 6;
    int lane = tid & 63;
    int g8 = lane >> 3;
    int fs = lane & 7;
    int node = blockIdx.x * 8 + w;   // grid*8 == 50000 exactly

    unsigned info = nodeinfo[node];
    float bv = bias[lane];
    int pos = (int)(info & 0x7FFFFFu);
    int nch = (int)(info >> 23) >> 3;
    const unsigned short* ip = csr + pos + g8;
    const uint4* Tp = (const uint4*)T;
    float a0 = 0.f, a1 = 0.f, a2 = 0.f, a3 = 0.f, a4 = 0.f, a5 = 0.f, a6 = 0.f, a7 = 0.f;
    int c = 0;
    for (; c + 4 <= nch; c += 4) {
        int j0 = ip[c * 8];
        int j1 = ip[c * 8 + 8];
        int j2 = ip[c * 8 + 16];
        int j3 = ip[c * 8 + 24];
        uint4 d0 = Tp[j0 * 8 + fs];
        uint4 d1 = Tp[j1 * 8 + fs];
        uint4 d2 = Tp[j2 * 8 + fs];
        uint4 d3 = Tp[j3 * 8 + fs];
        ACC8(d0) ACC8(d1) ACC8(d2) ACC8(d3)
    }
    if (c < nch) {
        int j0 = ip[c * 8];
        int j1 = ip[c * 8 + 8];
        uint4 d0 = Tp[j0 * 8 + fs];
        uint4 d1 = Tp[j1 * 8 + fs];
        ACC8(d0) ACC8(d1)
    }
    float4 pa = {a0, a1, a2, a3};
    float4 pb = {a4, a5, a6, a7};
    *(float4*)&part[w][g8][fs * 8] = pa;
    *(float4*)&part[w][g8][fs * 8 + 4] = pb;
    // part is wave-private: wave-internal DS ordering suffices, no barrier

    float acc = bv;
#pragma unroll
    for (int g = 0; g < 8; ++g) acc += part[w][g][lane];
    __builtin_nontemporal_store(acc, outp + (size_t)node * DIM + lane);
}

extern "C" void kernel_launch(void* const* d_in, const int* in_sizes, int n_in,
                              void* d_out, int out_size, void* d_ws, size_t ws_size,
                              hipStream_t stream) {
    const float* feat = (const float*)d_in[0];
    const int*   src  = (const int*)d_in[1];
    const int*   dst  = (const int*)d_in[2];
    const float* W1   = (const float*)d_in[3];
    const float* b1   = (const float*)d_in[4];
    const float* W2   = (const float*)d_in[5];
    const float* b2   = (const float*)d_in[6];
    float* out = (float*)d_out;

    // ws layout (~29 MB; harness poisons 256 MB of ws -> plenty)
    int*            binned   = (int*)d_ws;                                 // 196*12288 ints
    unsigned short* csr16    = (unsigned short*)(binned + NBK * CSR_CAP);  // 196*13312 ushort
    unsigned*       nodeinfo = (unsigned*)(csr16 + NBK * BCAP);            // 50000
    int*            bcur     = (int*)(nodeinfo + N_NODES);                 // 196*8*16 ints
    unsigned short* t        = (unsigned short*)(bcur + NBK * 8 * 16 + 8); // 50001*64 bf16
    unsigned short* t2       = t + (size_t)(N_NODES + 1) * 64;             // 50001*64 bf16

    // ---- binning + layer-1 transform (fused), CSR build ----
    (void)hipMemsetAsync(bcur, 0, NBK * 8 * 16 * sizeof(int), stream);
    bin_gemm1<<<BIN_BLOCKS + G1_BLOCKS, 256, 0, stream>>>(
        src, dst, bcur, binned, feat, W1, t);
    build_csr<<<NBK, 256, 0, stream>>>(binned, bcur, nodeinfo, csr16);

    // ---- Layer 1 aggregate + fused layer-2 transform: t2 = tanh(agg+b1)@W2^T ----
    agg_fuse1<<<NB_AGG8, 512, 0, stream>>>(t, csr16, nodeinfo, b1, W2, t2);

    // ---- Layer 2 aggregate: out = agg(t2) + b2, f32 ----
    agg_out<<<NB_AGG8, 512, 0, stream>>>(t2, csr16, nodeinfo, b2, out);
}

// Round 14
// 208.763 us; speedup vs baseline: 1.0039x; 1.0039x over previous
//
#include <hip/hip_runtime.h>

#define N_NODES 50000
#define N_EDGES 1600000
#define DIM 64
#define NBK 196          // buckets of 256 dst-nodes
#define BIN_BLOCKS 391   // ceil(1.6M / 4096)
#define CSR_CAP 12288    // per-bucket binned slots = 8 octants x OCT_CAP
#define OCT_CAP 1536     // per-(bucket,octant) slots (mean ~1021, +16 sigma)
#define BCAP 13312       // per-bucket csr16 slots (mean 8192 + pad<=3840 + 14-sigma)
#define G1_BLOCKS 391    // gemm1: 391*128 = 50048 >= 50001 nodes (incl. dummy)
#define NB_AGG8 6250     // agg blocks (8 nodes/block; 6250*8 == 50000 exactly)

// f32 -> bf16 round-to-nearest-even
__device__ __forceinline__ unsigned short f2bf(float f) {
    union { float f; unsigned u; } v; v.f = f;
    unsigned r = v.u + 0x7FFF + ((v.u >> 16) & 1);
    return (unsigned short)(r >> 16);
}
__device__ __forceinline__ float bf2f(unsigned short h) {
    union { unsigned u; float f; } v; v.u = ((unsigned)h) << 16;  return v.f;
}
// packed-bf16 halves of a uint -> f32 (low ushort, high ushort)
__device__ __forceinline__ float blo(unsigned u) {
    union { unsigned u; float f; } v; v.u = u << 16; return v.f;
}
__device__ __forceinline__ float bhi(unsigned u) {
    union { unsigned u; float f; } v; v.u = u & 0xFFFF0000u; return v.f;
}

// R27: binning SPLIT from gemm (R26 post-mortem: fused variants 46-49us vs
// split ~33-40 combined -- mixed-resource blocks schedule worse; and split
// puts bin_edges' isolated duration in the profile, ending 5 rounds of
// blind inference). 512 threads x 8 edges: register arrays halve (VGPR
// ~140 -> ~80) -> more waves/SIMD to overlap the serial component.
__global__ __launch_bounds__(512) void bin_edges(const int* __restrict__ src,
                                                 const int* __restrict__ dst,
                                                 int* __restrict__ bcur,
                                                 int* __restrict__ binned) {
    __shared__ int cnt[256];
    __shared__ int lofs[256];
    __shared__ int shiftv[256];
    __shared__ uint2 stag2[4096];   // 32 KB
    int tid = threadIdx.x;

    if (tid < 256) cnt[tid] = 0;
    __syncthreads();

    int base = blockIdx.x * 4096;
    int oct = blockIdx.x & 7;
    int nedge = N_EDGES - base;
    if (nedge > 4096) nedge = 4096;

    // Phase 1: pure load loop -- 16 independent global loads in flight
    int sreg[8], dreg[8];
#pragma unroll
    for (int i = 0; i < 8; ++i) {
        int e = base + i * 512 + tid;
        if (e < N_EDGES) { sreg[i] = src[e]; dreg[i] = dst[e]; }
        else             { sreg[i] = 0;      dreg[i] = -1; }
    }
    // Phase 2: LDS histogram with rank
    int myr[8];
#pragma unroll
    for (int i = 0; i < 8; ++i)
        if (dreg[i] >= 0) myr[i] = atomicAdd(&cnt[dreg[i] >> 8], 1);
    __syncthreads();

    // Phase 3: single-wave shuffle scan (R26), zero barriers inside
    if (tid < 64) {
        int c0 = cnt[tid * 4 + 0];
        int c1 = cnt[tid * 4 + 1];
        int c2 = cnt[tid * 4 + 2];
        int c3 = cnt[tid * 4 + 3];
        int t = c0 + c1 + c2 + c3;
        int p = t;
#pragma unroll
        for (int off = 1; off < 64; off <<= 1) {
            int u = __shfl_up(p, off);
            if (tid >= off) p += u;
        }
        int ex = p - t;
        int b0 = tid * 4;
        lofs[b0 + 0] = ex;
        lofs[b0 + 1] = ex + c0;
        lofs[b0 + 2] = ex + c0 + c1;
        lofs[b0 + 3] = ex + c0 + c1 + c2;
        if (b0 + 0 < NBK && c0) shiftv[b0 + 0] = (b0 + 0) * CSR_CAP + oct * OCT_CAP
            + atomicAdd(&bcur[((b0 + 0) * 8 + oct) * 16], c0) - lofs[b0 + 0];
        if (b0 + 1 < NBK && c1) shiftv[b0 + 1] = (b0 + 1) * CSR_CAP + oct * OCT_CAP
            + atomicAdd(&bcur[((b0 + 1) * 8 + oct) * 16], c1) - lofs[b0 + 1];
        if (b0 + 2 < NBK && c2) shiftv[b0 + 2] = (b0 + 2) * CSR_CAP + oct * OCT_CAP
            + atomicAdd(&bcur[((b0 + 2) * 8 + oct) * 16], c2) - lofs[b0 + 2];
        if (b0 + 3 < NBK && c3) shiftv[b0 + 3] = (b0 + 3) * CSR_CAP + oct * OCT_CAP
            + atomicAdd(&bcur[((b0 + 3) * 8 + oct) * 16], c3) - lofs[b0 + 3];
    }
    __syncthreads();

    // Phase 4: single b64 staging write per edge (payload + bucket)
#pragma unroll
    for (int i = 0; i < 8; ++i) {
        if (dreg[i] >= 0) {
            int b = dreg[i] >> 8;
            uint2 rec;
            rec.x = (unsigned)(((dreg[i] & 255) << 16) | sreg[i]);
            rec.y = (unsigned)b;
            stag2[lofs[b] + myr[i]] = rec;
        }
    }
    __syncthreads();

    // Phase 5: single b64 read per edge, semi-coalesced global write
    for (int i = tid; i < nedge; i += 512) {
        uint2 v = stag2[i];
        binned[i + shiftv[v.y]] = (int)v.x;
    }
}

// R21-verbatim gemm1 (standalone): T = feat @ W1^T (bf16). lane = output
// feature; W1 row in registers; X staged in LDS, wave-uniform broadcasts;
// 4 nodes in flight. Writes dummy zero row at node == N_NODES.
__global__ __launch_bounds__(256) void gemm1(const float* __restrict__ X,
                                             const float* __restrict__ W,
                                             unsigned short* __restrict__ T) {
    __shared__ __align__(16) float4 xs[128 * 16];   // 32 KB: 128 node rows
    int tid = threadIdx.x;
    int w = tid >> 6, lane = tid & 63;
    int nbase = blockIdx.x * 128;

    float4 wreg[16];
    const float4* wp = (const float4*)(W + lane * 64);
#pragma unroll
    for (int k4 = 0; k4 < 16; ++k4) wreg[k4] = wp[k4];

    const float4* xg = (const float4*)X;
    for (int L = tid; L < 2048; L += 256) {
        int row = nbase + (L >> 4);
        float4 v = {0.f, 0.f, 0.f, 0.f};
        if (row < N_NODES) v = xg[(size_t)row * 16 + (L & 15)];
        xs[L] = v;
    }
    __syncthreads();

    for (int g = 0; g < 8; ++g) {
        int n0 = w * 32 + g * 4;
        float accA = 0.f, accB = 0.f, accC = 0.f, accD = 0.f;
#pragma unroll
        for (int k4 = 0; k4 < 16; ++k4) {
            float4 w4 = wreg[k4];
            float4 xA = xs[(n0 + 0) * 16 + k4];   // wave-uniform -> broadcast
            float4 xB = xs[(n0 + 1) * 16 + k4];
            float4 xC = xs[(n0 + 2) * 16 + k4];
            float4 xD = xs[(n0 + 3) * 16 + k4];
            accA += xA.x * w4.x + xA.y * w4.y + xA.z * w4.z + xA.w * w4.w;
            accB += xB.x * w4.x + xB.y * w4.y + xB.z * w4.z + xB.w * w4.w;
            accC += xC.x * w4.x + xC.y * w4.y + xC.z * w4.z + xC.w * w4.w;
            accD += xD.x * w4.x + xD.y * w4.y + xD.z * w4.z + xD.w * w4.w;
        }
        int gn = nbase + n0;
        unsigned short vA = (gn + 0 == N_NODES) ? (unsigned short)0 : f2bf(accA);
        unsigned short vB = (gn + 1 == N_NODES) ? (unsigned short)0 : f2bf(accB);
        unsigned short vC = (gn + 2 == N_NODES) ? (unsigned short)0 : f2bf(accC);
        unsigned short vD = (gn + 3 == N_NODES) ? (unsigned short)0 : f2bf(accD);
        if (gn + 0 <= N_NODES) T[(size_t)(gn + 0) * 64 + lane] = vA;
        if (gn + 1 <= N_NODES) T[(size_t)(gn + 1) * 64 + lane] = vB;
        if (gn + 2 <= N_NODES) T[(size_t)(gn + 2) * 64 + lane] = vC;
        if (gn + 3 <= N_NODES) T[(size_t)(gn + 3) * 64 + lane] = vD;
    }
}

// R24-verbatim build_csr (single-pass per bucket + depth-4 prefetch).
__global__ __launch_bounds__(256) void build_csr(const int* __restrict__ binned,
                                                 const int* __restrict__ bcur,
                                                 unsigned* __restrict__ nodeinfo,
                                                 unsigned short* __restrict__ csr16) {
    __shared__ int cnt[256], cnt2[256], ofs[256], sb[256];
    __shared__ int mo[8];
    int tid = threadIdx.x;
    int b = blockIdx.x;
    int bbase = b * BCAP;
    cnt[tid] = 0; cnt2[tid] = 0;
    if (tid < 8) {
        int m = bcur[(b * 8 + tid) * 16];
        mo[tid] = m > OCT_CAP ? OCT_CAP : m;
    }
    __syncthreads();

    for (int oct = 0; oct < 8; ++oct) {
        const int* ib = binned + b * CSR_CAP + oct * OCT_CAP;
        int m = mo[oct];
        int i = tid;
        for (; i + 768 < m; i += 1024) {
            int p0 = ib[i], p1 = ib[i + 256], p2 = ib[i + 512], p3 = ib[i + 768];
            atomicAdd(&cnt[(p0 >> 16) & 255], 1);
            atomicAdd(&cnt[(p1 >> 16) & 255], 1);
            atomicAdd(&cnt[(p2 >> 16) & 255], 1);
            atomicAdd(&cnt[(p3 >> 16) & 255], 1);
        }
        for (; i < m; i += 256)
            atomicAdd(&cnt[(ib[i] >> 16) & 255], 1);
    }
    __syncthreads();

    int myc = cnt[tid];
    int v = (myc + 15) & ~15;          // mult-16 pad
    sb[tid] = v;
    __syncthreads();
    for (int off = 1; off < 256; off <<= 1) {
        int u = (tid >= off) ? sb[tid - off] : 0;
        __syncthreads();
        sb[tid] += u;
        __syncthreads();
    }
    int o = sb[tid] - v;
    ofs[tid] = o;
    int node = (b << 8) + tid;
    if (node < N_NODES)
        nodeinfo[node] = ((unsigned)v << 23) | (unsigned)(bbase + o);
    for (int i = myc; i < v; ++i)       // pad tail with dummy src
        csr16[bbase + o + i] = (unsigned short)N_NODES;
    __syncthreads();

    for (int oct = 0; oct < 8; ++oct) {
        const int* ib = binned + b * CSR_CAP + oct * OCT_CAP;
        int m = mo[oct];
        int i = tid;
        for (; i + 768 < m; i += 1024) {
            int p0 = ib[i], p1 = ib[i + 256], p2 = ib[i + 512], p3 = ib[i + 768];
            int d0 = (p0 >> 16) & 255, d1 = (p1 >> 16) & 255;
            int d2 = (p2 >> 16) & 255, d3 = (p3 >> 16) & 255;
            int r0 = atomicAdd(&cnt2[d0], 1);
            int r1 = atomicAdd(&cnt2[d1], 1);
            int r2 = atomicAdd(&cnt2[d2], 1);
            int r3 = atomicAdd(&cnt2[d3], 1);
            csr16[bbase + ofs[d0] + r0] = (unsigned short)(p0 & 0xFFFF);
            csr16[bbase + ofs[d1] + r1] = (unsigned short)(p1 & 0xFFFF);
            csr16[bbase + ofs[d2] + r2] = (unsigned short)(p2 & 0xFFFF);
            csr16[bbase + ofs[d3] + r3] = (unsigned short)(p3 & 0xFFFF);
        }
        for (; i < m; i += 256) {
            int p = ib[i];
            int dl = (p >> 16) & 255;
            int r = atomicAdd(&cnt2[dl], 1);
            csr16[bbase + ofs[dl] + r] = (unsigned short)(p & 0xFFFF);
        }
    }
}

// Accumulate one uint4 (8 bf16 feature values) into 8 f32 accumulators.
#define ACC8(d)                                                     \
    a0 += blo(d.x); a1 += bhi(d.x); a2 += blo(d.y); a3 += bhi(d.y); \
    a4 += blo(d.z); a5 += bhi(d.z); a6 += blo(d.w); a7 += bhi(d.w);

// R23-verbatim agg_fuse1 (at the ~2-sector/edge TCP miss-handling floor --
// R17/R19/R22 proved hit-tier/occupancy/request-width invariance).
__global__ __launch_bounds__(512) void agg_fuse1(const unsigned short* __restrict__ T,
                                                 const unsigned short* __restrict__ csr,
                                                 const unsigned* __restrict__ nodeinfo,
                                                 const float* __restrict__ b1,
                                                 const float* __restrict__ W2,
                                                 unsigned short* __restrict__ T2) {
    __shared__ __align__(16) float4 W2t4[1024];     // 16 KB (W2 transposed, lane-striped)
    __shared__ __align__(16) float part[8][8][72];  // 18 KB (per-wave partials; row0 doubles as h)
    int tid = threadIdx.x;
    int w = tid >> 6;
    int lane = tid & 63;
    int g8 = lane >> 3;
    int fs = lane & 7;
    int node = blockIdx.x * 8 + w;

    for (int L4 = tid; L4 < 1024; L4 += 512) {
        int k4 = L4 >> 6, f = L4 & 63;
        W2t4[L4] = *(const float4*)(W2 + f * 64 + k4 * 4);
    }

    unsigned info = nodeinfo[node];
    float bias = b1[lane];
    int pos = (int)(info & 0x7FFFFFu);
    int nch = (int)(info >> 23) >> 3;   // 8-edge chunks, even (pcnt mult 16)
    const unsigned short* ip = csr + pos + g8;
    const uint4* Tp = (const uint4*)T;
    float a0 = 0.f, a1 = 0.f, a2 = 0.f, a3 = 0.f, a4 = 0.f, a5 = 0.f, a6 = 0.f, a7 = 0.f;
    int c = 0;
    for (; c + 4 <= nch; c += 4) {
        int j0 = ip[c * 8];
        int j1 = ip[c * 8 + 8];
        int j2 = ip[c * 8 + 16];
        int j3 = ip[c * 8 + 24];
        uint4 d0 = Tp[j0 * 8 + fs];
        uint4 d1 = Tp[j1 * 8 + fs];
        uint4 d2 = Tp[j2 * 8 + fs];
        uint4 d3 = Tp[j3 * 8 + fs];
        ACC8(d0) ACC8(d1) ACC8(d2) ACC8(d3)
    }
    if (c < nch) {   // remaining 2 chunks (nch even)
        int j0 = ip[c * 8];
        int j1 = ip[c * 8 + 8];
        uint4 d0 = Tp[j0 * 8 + fs];
        uint4 d1 = Tp[j1 * 8 + fs];
        ACC8(d0) ACC8(d1)
    }
    float4 pa = {a0, a1, a2, a3};
    float4 pb = {a4, a5, a6, a7};
    *(float4*)&part[w][g8][fs * 8] = pa;
    *(float4*)&part[w][g8][fs * 8 + 4] = pb;
    __syncthreads();   // covers W2t4 staging (part is wave-private)

    float acc = bias;
#pragma unroll
    for (int g = 0; g < 8; ++g) acc += part[w][g][lane];

    float e = __expf(2.f * acc);
    part[w][0][lane] = 1.f - 2.f / (e + 1.f);   // after all part reads (lockstep wave)

    const float* hrow = &part[w][0][0];
    float tf = 0.f;
#pragma unroll
    for (int k4 = 0; k4 < 16; ++k4) {
        float4 hv = *(const float4*)(hrow + k4 * 4);   // broadcast
        float4 wv = W2t4[k4 * 64 + lane];
        tf += hv.x * wv.x + hv.y * wv.y + hv.z * wv.z + hv.w * wv.w;
    }
    T2[(size_t)node * DIM + lane] = f2bf(tf);

    // zero T2's dummy pad row (block 0 only; agg2 gathers it for padding)
    if (blockIdx.x == 0 && tid < 64)
        T2[(size_t)N_NODES * DIM + tid] = 0;
}

// R23-verbatim agg_out (scattered-gather floor). No barrier.
__global__ __launch_bounds__(512) void agg_out(const unsigned short* __restrict__ T,
                                               const unsigned short* __restrict__ csr,
                                               const unsigned* __restrict__ nodeinfo,
                                               const float* __restrict__ bias,
                                               float* __restrict__ outp) {
    __shared__ __align__(16) float part[8][8][72];  // 18 KB, wave-private
    int tid = threadIdx.x;
    int w = tid >> 6;
    int lane = tid & 63;
    int g8 = lane >> 3;
    int fs = lane & 7;
    int node = blockIdx.x * 8 + w;   // grid*8 == 50000 exactly

    unsigned info = nodeinfo[node];
    float bv = bias[lane];
    int pos = (int)(info & 0x7FFFFFu);
    int nch = (int)(info >> 23) >> 3;
    const unsigned short* ip = csr + pos + g8;
    const uint4* Tp = (const uint4*)T;
    float a0 = 0.f, a1 = 0.f, a2 = 0.f, a3 = 0.f, a4 = 0.f, a5 = 0.f, a6 = 0.f, a7 = 0.f;
    int c = 0;
    for (; c + 4 <= nch; c += 4) {
        int j0 = ip[c * 8];
        int j1 = ip[c * 8 + 8];
        int j2 = ip[c * 8 + 16];
        int j3 = ip[c * 8 + 24];
        uint4 d0 = Tp[j0 * 8 + fs];
        uint4 d1 = Tp[j1 * 8 + fs];
        uint4 d2 = Tp[j2 * 8 + fs];
        uint4 d3 = Tp[j3 * 8 + fs];
        ACC8(d0) ACC8(d1) ACC8(d2) ACC8(d3)
    }
    if (c < nch) {
        int j0 = ip[c * 8];
        int j1 = ip[c * 8 + 8];
        uint4 d0 = Tp[j0 * 8 + fs];
        uint4 d1 = Tp[j1 * 8 + fs];
        ACC8(d0) ACC8(d1)
    }
    float4 pa = {a0, a1, a2, a3};
    float4 pb = {a4, a5, a6, a7};
    *(float4*)&part[w][g8][fs * 8] = pa;
    *(float4*)&part[w][g8][fs * 8 + 4] = pb;
    // part is wave-private: wave-internal DS ordering suffices, no barrier

    float acc = bv;
#pragma unroll
    for (int g = 0; g < 8; ++g) acc += part[w][g][lane];
    __builtin_nontemporal_store(acc, outp + (size_t)node * DIM + lane);
}

extern "C" void kernel_launch(void* const* d_in, const int* in_sizes, int n_in,
                              void* d_out, int out_size, void* d_ws, size_t ws_size,
                              hipStream_t stream) {
    const float* feat = (const float*)d_in[0];
    const int*   src  = (const int*)d_in[1];
    const int*   dst  = (const int*)d_in[2];
    const float* W1   = (const float*)d_in[3];
    const float* b1   = (const float*)d_in[4];
    const float* W2   = (const float*)d_in[5];
    const float* b2   = (const float*)d_in[6];
    float* out = (float*)d_out;

    // ws layout (~29 MB; harness poisons 256 MB of ws -> plenty)
    int*            binned   = (int*)d_ws;                                 // 196*12288 ints
    unsigned short* csr16    = (unsigned short*)(binned + NBK * CSR_CAP);  // 196*13312 ushort
    unsigned*       nodeinfo = (unsigned*)(csr16 + NBK * BCAP);            // 50000
    int*            bcur     = (int*)(nodeinfo + N_NODES);                 // 196*8*16 ints
    unsigned short* t        = (unsigned short*)(bcur + NBK * 8 * 16 + 8); // 50001*64 bf16
    unsigned short* t2       = t + (size_t)(N_NODES + 1) * 64;             // 50001*64 bf16

    // ---- binning, layer-1 transform, CSR build (split for scheduling + counters) ----
    (void)hipMemsetAsync(bcur, 0, NBK * 8 * 16 * sizeof(int), stream);
    bin_edges<<<BIN_BLOCKS, 512, 0, stream>>>(src, dst, bcur, binned);
    gemm1<<<G1_BLOCKS, 256, 0, stream>>>(feat, W1, t);
    build_csr<<<NBK, 256, 0, stream>>>(binned, bcur, nodeinfo, csr16);

    // ---- Layer 1 aggregate + fused layer-2 transform: t2 = tanh(agg+b1)@W2^T ----
    agg_fuse1<<<NB_AGG8, 512, 0, stream>>>(t, csr16, nodeinfo, b1, W2, t2);

    // ---- Layer 2 aggregate: out = agg(t2) + b2, f32 ----
    agg_out<<<NB_AGG8, 512, 0, stream>>>(t2, csr16, nodeinfo, b2, out);
}

// Round 15
// 203.508 us; speedup vs baseline: 1.0298x; 1.0258x over previous
//
#include <hip/hip_runtime.h>

#define N_NODES 50000
#define N_EDGES 1600000
#define DIM 64
#define NBK 196          // buckets of 256 dst-nodes
#define BIN_BLOCKS 391   // ceil(1.6M / 4096)
#define CSR_CAP 12288    // per-bucket binned slots = 8 octants x OCT_CAP
#define OCT_CAP 1536     // per-(bucket,octant) slots (mean ~1021, +16 sigma)
#define BCAP 13312       // per-bucket csr16 slots (mean 8192 + pad<=3840 + 14-sigma)
#define G1_BLOCKS 391    // gemm1: 391*128 = 50048 >= 50001 nodes (incl. dummy)
#define NB_AGG8 6250     // agg blocks (8 nodes/block; 6250*8 == 50000 exactly)

// f32 -> bf16 round-to-nearest-even
__device__ __forceinline__ unsigned short f2bf(float f) {
    union { float f; unsigned u; } v; v.f = f;
    unsigned r = v.u + 0x7FFF + ((v.u >> 16) & 1);
    return (unsigned short)(r >> 16);
}
__device__ __forceinline__ float bf2f(unsigned short h) {
    union { unsigned u; float f; } v; v.u = ((unsigned)h) << 16;  return v.f;
}
// packed-bf16 halves of a uint -> f32 (low ushort, high ushort)
__device__ __forceinline__ float blo(unsigned u) {
    union { unsigned u; float f; } v; v.u = u << 16; return v.f;
}
__device__ __forceinline__ float bhi(unsigned u) {
    union { unsigned u; float f; } v; v.u = u & 0xFFFF0000u; return v.f;
}

// R27-verbatim bin_edges: 512 threads x 8 edges, phase-split loads, 8B LDS
// records, single-wave shuffle scan, oct-split bcur.
__global__ __launch_bounds__(512) void bin_edges(const int* __restrict__ src,
                                                 const int* __restrict__ dst,
                                                 int* __restrict__ bcur,
                                                 int* __restrict__ binned) {
    __shared__ int cnt[256];
    __shared__ int lofs[256];
    __shared__ int shiftv[256];
    __shared__ uint2 stag2[4096];   // 32 KB
    int tid = threadIdx.x;

    if (tid < 256) cnt[tid] = 0;
    __syncthreads();

    int base = blockIdx.x * 4096;
    int oct = blockIdx.x & 7;
    int nedge = N_EDGES - base;
    if (nedge > 4096) nedge = 4096;

    // Phase 1: pure load loop -- 16 independent global loads in flight
    int sreg[8], dreg[8];
#pragma unroll
    for (int i = 0; i < 8; ++i) {
        int e = base + i * 512 + tid;
        if (e < N_EDGES) { sreg[i] = src[e]; dreg[i] = dst[e]; }
        else             { sreg[i] = 0;      dreg[i] = -1; }
    }
    // Phase 2: LDS histogram with rank
    int myr[8];
#pragma unroll
    for (int i = 0; i < 8; ++i)
        if (dreg[i] >= 0) myr[i] = atomicAdd(&cnt[dreg[i] >> 8], 1);
    __syncthreads();

    // Phase 3: single-wave shuffle scan, zero barriers inside
    if (tid < 64) {
        int c0 = cnt[tid * 4 + 0];
        int c1 = cnt[tid * 4 + 1];
        int c2 = cnt[tid * 4 + 2];
        int c3 = cnt[tid * 4 + 3];
        int t = c0 + c1 + c2 + c3;
        int p = t;
#pragma unroll
        for (int off = 1; off < 64; off <<= 1) {
            int u = __shfl_up(p, off);
            if (tid >= off) p += u;
        }
        int ex = p - t;
        int b0 = tid * 4;
        lofs[b0 + 0] = ex;
        lofs[b0 + 1] = ex + c0;
        lofs[b0 + 2] = ex + c0 + c1;
        lofs[b0 + 3] = ex + c0 + c1 + c2;
        if (b0 + 0 < NBK && c0) shiftv[b0 + 0] = (b0 + 0) * CSR_CAP + oct * OCT_CAP
            + atomicAdd(&bcur[((b0 + 0) * 8 + oct) * 16], c0) - lofs[b0 + 0];
        if (b0 + 1 < NBK && c1) shiftv[b0 + 1] = (b0 + 1) * CSR_CAP + oct * OCT_CAP
            + atomicAdd(&bcur[((b0 + 1) * 8 + oct) * 16], c1) - lofs[b0 + 1];
        if (b0 + 2 < NBK && c2) shiftv[b0 + 2] = (b0 + 2) * CSR_CAP + oct * OCT_CAP
            + atomicAdd(&bcur[((b0 + 2) * 8 + oct) * 16], c2) - lofs[b0 + 2];
        if (b0 + 3 < NBK && c3) shiftv[b0 + 3] = (b0 + 3) * CSR_CAP + oct * OCT_CAP
            + atomicAdd(&bcur[((b0 + 3) * 8 + oct) * 16], c3) - lofs[b0 + 3];
    }
    __syncthreads();

    // Phase 4: single b64 staging write per edge (payload + bucket)
#pragma unroll
    for (int i = 0; i < 8; ++i) {
        if (dreg[i] >= 0) {
            int b = dreg[i] >> 8;
            uint2 rec;
            rec.x = (unsigned)(((dreg[i] & 255) << 16) | sreg[i]);
            rec.y = (unsigned)b;
            stag2[lofs[b] + myr[i]] = rec;
        }
    }
    __syncthreads();

    // Phase 5: single b64 read per edge, semi-coalesced global write
    for (int i = tid; i < nedge; i += 512) {
        uint2 v = stag2[i];
        binned[i + shiftv[v.y]] = (int)v.x;
    }
}

// R28: build_csr FUSED with gemm1 in one dispatch. gemm1 depends only on
// feat/W1 (not on bin_edges/build_csr), so blocks 196.. run it concurrently
// with csr blocks 0..195 -- hides gemm1's ~8us entirely and removes one
// launch gap. Both paths 256 threads; union'd 32KB LDS.
__global__ __launch_bounds__(256) void csr_gemm1(const int* __restrict__ binned,
                                                 const int* __restrict__ bcur,
                                                 unsigned* __restrict__ nodeinfo,
                                                 unsigned short* __restrict__ csr16,
                                                 const float* __restrict__ X,
                                                 const float* __restrict__ W,
                                                 unsigned short* __restrict__ T) {
    __shared__ __align__(16) char smem[32768];
    int tid = threadIdx.x;

    if (blockIdx.x >= NBK) {
        // ---------------- GEMM path (R21-proven): T = X @ W^T ----------------
        float4* xs = (float4*)smem;      // 128 node rows x 16 float4 = 32KB
        int w = tid >> 6, lane = tid & 63;
        int nbase = (blockIdx.x - NBK) * 128;

        float4 wreg[16];
        const float4* wp = (const float4*)(W + lane * 64);
#pragma unroll
        for (int k4 = 0; k4 < 16; ++k4) wreg[k4] = wp[k4];

        const float4* xg = (const float4*)X;
        for (int L = tid; L < 2048; L += 256) {
            int row = nbase + (L >> 4);
            float4 v = {0.f, 0.f, 0.f, 0.f};
            if (row < N_NODES) v = xg[(size_t)row * 16 + (L & 15)];
            xs[L] = v;
        }
        __syncthreads();

        for (int g = 0; g < 8; ++g) {
            int n0 = w * 32 + g * 4;
            float accA = 0.f, accB = 0.f, accC = 0.f, accD = 0.f;
#pragma unroll
            for (int k4 = 0; k4 < 16; ++k4) {
                float4 w4 = wreg[k4];
                float4 xA = xs[(n0 + 0) * 16 + k4];   // wave-uniform -> broadcast
                float4 xB = xs[(n0 + 1) * 16 + k4];
                float4 xC = xs[(n0 + 2) * 16 + k4];
                float4 xD = xs[(n0 + 3) * 16 + k4];
                accA += xA.x * w4.x + xA.y * w4.y + xA.z * w4.z + xA.w * w4.w;
                accB += xB.x * w4.x + xB.y * w4.y + xB.z * w4.z + xB.w * w4.w;
                accC += xC.x * w4.x + xC.y * w4.y + xC.z * w4.z + xC.w * w4.w;
                accD += xD.x * w4.x + xD.y * w4.y + xD.z * w4.z + xD.w * w4.w;
            }
            int gn = nbase + n0;
            unsigned short vA = (gn + 0 == N_NODES) ? (unsigned short)0 : f2bf(accA);
            unsigned short vB = (gn + 1 == N_NODES) ? (unsigned short)0 : f2bf(accB);
            unsigned short vC = (gn + 2 == N_NODES) ? (unsigned short)0 : f2bf(accC);
            unsigned short vD = (gn + 3 == N_NODES) ? (unsigned short)0 : f2bf(accD);
            if (gn + 0 <= N_NODES) T[(size_t)(gn + 0) * 64 + lane] = vA;
            if (gn + 1 <= N_NODES) T[(size_t)(gn + 1) * 64 + lane] = vB;
            if (gn + 2 <= N_NODES) T[(size_t)(gn + 2) * 64 + lane] = vC;
            if (gn + 3 <= N_NODES) T[(size_t)(gn + 3) * 64 + lane] = vD;
        }
        return;
    }

    // ---------------- CSR path (R24-proven, single-pass + prefetch) ----------------
    int* cnt  = (int*)smem;            // 4 x 256 ints + mo[8]
    int* cnt2 = cnt + 256;
    int* ofs  = cnt2 + 256;
    int* sb   = ofs + 256;
    int* mo   = sb + 256;
    int b = blockIdx.x;
    int bbase = b * BCAP;
    cnt[tid] = 0; cnt2[tid] = 0;
    if (tid < 8) {
        int m = bcur[(b * 8 + tid) * 16];
        mo[tid] = m > OCT_CAP ? OCT_CAP : m;
    }
    __syncthreads();

    for (int oct = 0; oct < 8; ++oct) {
        const int* ib = binned + b * CSR_CAP + oct * OCT_CAP;
        int m = mo[oct];
        int i = tid;
        for (; i + 768 < m; i += 1024) {
            int p0 = ib[i], p1 = ib[i + 256], p2 = ib[i + 512], p3 = ib[i + 768];
            atomicAdd(&cnt[(p0 >> 16) & 255], 1);
            atomicAdd(&cnt[(p1 >> 16) & 255], 1);
            atomicAdd(&cnt[(p2 >> 16) & 255], 1);
            atomicAdd(&cnt[(p3 >> 16) & 255], 1);
        }
        for (; i < m; i += 256)
            atomicAdd(&cnt[(ib[i] >> 16) & 255], 1);
    }
    __syncthreads();

    int myc = cnt[tid];
    int v = (myc + 15) & ~15;          // mult-16 pad
    sb[tid] = v;
    __syncthreads();
    for (int off = 1; off < 256; off <<= 1) {
        int u = (tid >= off) ? sb[tid - off] : 0;
        __syncthreads();
        sb[tid] += u;
        __syncthreads();
    }
    int o = sb[tid] - v;
    ofs[tid] = o;
    int node = (b << 8) + tid;
    if (node < N_NODES)
        nodeinfo[node] = ((unsigned)v << 23) | (unsigned)(bbase + o);
    for (int i = myc; i < v; ++i)       // pad tail with dummy src
        csr16[bbase + o + i] = (unsigned short)N_NODES;
    __syncthreads();

    for (int oct = 0; oct < 8; ++oct) {
        const int* ib = binned + b * CSR_CAP + oct * OCT_CAP;
        int m = mo[oct];
        int i = tid;
        for (; i + 768 < m; i += 1024) {
            int p0 = ib[i], p1 = ib[i + 256], p2 = ib[i + 512], p3 = ib[i + 768];
            int d0 = (p0 >> 16) & 255, d1 = (p1 >> 16) & 255;
            int d2 = (p2 >> 16) & 255, d3 = (p3 >> 16) & 255;
            int r0 = atomicAdd(&cnt2[d0], 1);
            int r1 = atomicAdd(&cnt2[d1], 1);
            int r2 = atomicAdd(&cnt2[d2], 1);
            int r3 = atomicAdd(&cnt2[d3], 1);
            csr16[bbase + ofs[d0] + r0] = (unsigned short)(p0 & 0xFFFF);
            csr16[bbase + ofs[d1] + r1] = (unsigned short)(p1 & 0xFFFF);
            csr16[bbase + ofs[d2] + r2] = (unsigned short)(p2 & 0xFFFF);
            csr16[bbase + ofs[d3] + r3] = (unsigned short)(p3 & 0xFFFF);
        }
        for (; i < m; i += 256) {
            int p = ib[i];
            int dl = (p >> 16) & 255;
            int r = atomicAdd(&cnt2[dl], 1);
            csr16[bbase + ofs[dl] + r] = (unsigned short)(p & 0xFFFF);
        }
    }
}

// Accumulate one uint4 (8 bf16 feature values) into 8 f32 accumulators.
#define ACC8(d)                                                     \
    a0 += blo(d.x); a1 += bhi(d.x); a2 += blo(d.y); a3 += bhi(d.y); \
    a4 += blo(d.z); a5 += bhi(d.z); a6 += blo(d.w); a7 += bhi(d.w);

// R23-verbatim agg_fuse1 (at the ~2-sector/edge scattered-request floor --
// R17/R19/R22 proved hit-tier/occupancy/request-width invariance).
__global__ __launch_bounds__(512) void agg_fuse1(const unsigned short* __restrict__ T,
                                                 const unsigned short* __restrict__ csr,
                                                 const unsigned* __restrict__ nodeinfo,
                                                 const float* __restrict__ b1,
                                                 const float* __restrict__ W2,
                                                 unsigned short* __restrict__ T2) {
    __shared__ __align__(16) float4 W2t4[1024];     // 16 KB (W2 transposed, lane-striped)
    __shared__ __align__(16) float part[8][8][72];  // 18 KB (per-wave partials; row0 doubles as h)
    int tid = threadIdx.x;
    int w = tid >> 6;
    int lane = tid & 63;
    int g8 = lane >> 3;
    int fs = lane & 7;
    int node = blockIdx.x * 8 + w;

    for (int L4 = tid; L4 < 1024; L4 += 512) {
        int k4 = L4 >> 6, f = L4 & 63;
        W2t4[L4] = *(const float4*)(W2 + f * 64 + k4 * 4);
    }

    unsigned info = nodeinfo[node];
    float bias = b1[lane];
    int pos = (int)(info & 0x7FFFFFu);
    int nch = (int)(info >> 23) >> 3;   // 8-edge chunks, even (pcnt mult 16)
    const unsigned short* ip = csr + pos + g8;
    const uint4* Tp = (const uint4*)T;
    float a0 = 0.f, a1 = 0.f, a2 = 0.f, a3 = 0.f, a4 = 0.f, a5 = 0.f, a6 = 0.f, a7 = 0.f;
    int c = 0;
    for (; c + 4 <= nch; c += 4) {
        int j0 = ip[c * 8];
        int j1 = ip[c * 8 + 8];
        int j2 = ip[c * 8 + 16];
        int j3 = ip[c * 8 + 24];
        uint4 d0 = Tp[j0 * 8 + fs];
        uint4 d1 = Tp[j1 * 8 + fs];
        uint4 d2 = Tp[j2 * 8 + fs];
        uint4 d3 = Tp[j3 * 8 + fs];
        ACC8(d0) ACC8(d1) ACC8(d2) ACC8(d3)
    }
    if (c < nch) {   // remaining 2 chunks (nch even)
        int j0 = ip[c * 8];
        int j1 = ip[c * 8 + 8];
        uint4 d0 = Tp[j0 * 8 + fs];
        uint4 d1 = Tp[j1 * 8 + fs];
        ACC8(d0) ACC8(d1)
    }
    float4 pa = {a0, a1, a2, a3};
    float4 pb = {a4, a5, a6, a7};
    *(float4*)&part[w][g8][fs * 8] = pa;
    *(float4*)&part[w][g8][fs * 8 + 4] = pb;
    __syncthreads();   // covers W2t4 staging (part is wave-private)

    float acc = bias;
#pragma unroll
    for (int g = 0; g < 8; ++g) acc += part[w][g][lane];

    float e = __expf(2.f * acc);
    part[w][0][lane] = 1.f - 2.f / (e + 1.f);   // after all part reads (lockstep wave)

    const float* hrow = &part[w][0][0];
    float tf = 0.f;
#pragma unroll
    for (int k4 = 0; k4 < 16; ++k4) {
        float4 hv = *(const float4*)(hrow + k4 * 4);   // broadcast
        float4 wv = W2t4[k4 * 64 + lane];
        tf += hv.x * wv.x + hv.y * wv.y + hv.z * wv.z + hv.w * wv.w;
    }
    T2[(size_t)node * DIM + lane] = f2bf(tf);

    // zero T2's dummy pad row (block 0 only; agg2 gathers it for padding)
    if (blockIdx.x == 0 && tid < 64)
        T2[(size_t)N_NODES * DIM + tid] = 0;
}

// R23-verbatim agg_out (scattered-gather floor). No barrier.
__global__ __launch_bounds__(512) void agg_out(const unsigned short* __restrict__ T,
                                               const unsigned short* __restrict__ csr,
                                               const unsigned* __restrict__ nodeinfo,
                                               const float* __restrict__ bias,
                                               float* __restrict__ outp) {
    __shared__ __align__(16) float part[8][8][72];  // 18 KB, wave-private
    int tid = threadIdx.x;
    int w = tid >> 6;
    int lane = tid & 63;
    int g8 = lane >> 3;
    int fs = lane & 7;
    int node = blockIdx.x * 8 + w;   // grid*8 == 50000 exactly

    unsigned info = nodeinfo[node];
    float bv = bias[lane];
    int pos = (int)(info & 0x7FFFFFu);
    int nch = (int)(info >> 23) >> 3;
    const unsigned short* ip = csr + pos + g8;
    const uint4* Tp = (const uint4*)T;
    float a0 = 0.f, a1 = 0.f, a2 = 0.f, a3 = 0.f, a4 = 0.f, a5 = 0.f, a6 = 0.f, a7 = 0.f;
    int c = 0;
    for (; c + 4 <= nch; c += 4) {
        int j0 = ip[c * 8];
        int j1 = ip[c * 8 + 8];
        int j2 = ip[c * 8 + 16];
        int j3 = ip[c * 8 + 24];
        uint4 d0 = Tp[j0 * 8 + fs];
        uint4 d1 = Tp[j1 * 8 + fs];
        uint4 d2 = Tp[j2 * 8 + fs];
        uint4 d3 = Tp[j3 * 8 + fs];
        ACC8(d0) ACC8(d1) ACC8(d2) ACC8(d3)
    }
    if (c < nch) {
        int j0 = ip[c * 8];
        int j1 = ip[c * 8 + 8];
        uint4 d0 = Tp[j0 * 8 + fs];
        uint4 d1 = Tp[j1 * 8 + fs];
        ACC8(d0) ACC8(d1)
    }
    float4 pa = {a0, a1, a2, a3};
    float4 pb = {a4, a5, a6, a7};
    *(float4*)&part[w][g8][fs * 8] = pa;
    *(float4*)&part[w][g8][fs * 8 + 4] = pb;
    // part is wave-private: wave-internal DS ordering suffices, no barrier

    float acc = bv;
#pragma unroll
    for (int g = 0; g < 8; ++g) acc += part[w][g][lane];
    __builtin_nontemporal_store(acc, outp + (size_t)node * DIM + lane);
}

extern "C" void kernel_launch(void* const* d_in, const int* in_sizes, int n_in,
                              void* d_out, int out_size, void* d_ws, size_t ws_size,
                              hipStream_t stream) {
    const float* feat = (const float*)d_in[0];
    const int*   src  = (const int*)d_in[1];
    const int*   dst  = (const int*)d_in[2];
    const float* W1   = (const float*)d_in[3];
    const float* b1   = (const float*)d_in[4];
    const float* W2   = (const float*)d_in[5];
    const float* b2   = (const float*)d_in[6];
    float* out = (float*)d_out;

    // ws layout (~29 MB; harness poisons 256 MB of ws -> plenty)
    int*            binned   = (int*)d_ws;                                 // 196*12288 ints
    unsigned short* csr16    = (unsigned short*)(binned + NBK * CSR_CAP);  // 196*13312 ushort
    unsigned*       nodeinfo = (unsigned*)(csr16 + NBK * BCAP);            // 50000
    int*            bcur     = (int*)(nodeinfo + N_NODES);                 // 196*8*16 ints
    unsigned short* t        = (unsigned short*)(bcur + NBK * 8 * 16 + 8); // 50001*64 bf16
    unsigned short* t2       = t + (size_t)(N_NODES + 1) * 64;             // 50001*64 bf16

    // ---- binning; then CSR build + layer-1 transform CONCURRENT (one dispatch) ----
    (void)hipMemsetAsync(bcur, 0, NBK * 8 * 16 * sizeof(int), stream);
    bin_edges<<<BIN_BLOCKS, 512, 0, stream>>>(src, dst, bcur, binned);
    csr_gemm1<<<NBK + G1_BLOCKS, 256, 0, stream>>>(
        binned, bcur, nodeinfo, csr16, feat, W1, t);

    // ---- Layer 1 aggregate + fused layer-2 transform: t2 = tanh(agg+b1)@W2^T ----
    agg_fuse1<<<NB_AGG8, 512, 0, stream>>>(t, csr16, nodeinfo, b1, W2, t2);

    // ---- Layer 2 aggregate: out = agg(t2) + b2, f32 ----
    agg_out<<<NB_AGG8, 512, 0, stream>>>(t2, csr16, nodeinfo, b2, out);
}